// Round 11
// baseline (8660.908 us; speedup 1.0000x reference)
//
#include <hip/hip_runtime.h>
#include <hip/hip_bf16.h>

#define TT 2048
#define BB 32
#define DD 256
#define HH 256
#define GG 768   // 3*H

typedef _Float16 half2_t __attribute__((ext_vector_type(2)));
typedef _Float16 f16x8 __attribute__((ext_vector_type(8)));
typedef float    f32x4 __attribute__((ext_vector_type(4)));

__device__ inline float fdot2(unsigned int w, unsigned int h, float acc) {
#if __has_builtin(__builtin_amdgcn_fdot2)
    return __builtin_amdgcn_fdot2(__builtin_bit_cast(half2_t, w),
                                  __builtin_bit_cast(half2_t, h), acc, false);
#else
    half2_t a = __builtin_bit_cast(half2_t, w);
    half2_t b = __builtin_bit_cast(half2_t, h);
    return acc + (float)a.x * (float)b.x + (float)a.y * (float)b.y;
#endif
}

// ---------- helpers for fp32/bf16 workspace storage of gi ----------
__device__ inline float ldgi(const float* p) { return *p; }
__device__ inline float ldgi(const __hip_bfloat16* p) { return __bfloat162float(*p); }
__device__ inline void stgi(float* p, float v) { *p = v; }
__device__ inline void stgi(__hip_bfloat16* p, float v) { *p = __float2bfloat16(v); }

// ---------- pack w_hh into the 4-way split layout ----------
// flat uint4 index e = (q*32 + g4)*192 + r'  (r' = gate*64 + jj)
//   -> w_hh row n = gate*256 + q*64 + jj, k = g4*8 + 2c (f16 pair {k,k+1})
__global__ __launch_bounds__(256)
void pack_w(const float* __restrict__ w, unsigned int* __restrict__ wf) {
    int i = blockIdx.x * 256 + threadIdx.x;  // 0 .. 98303
    int c  = i & 3;
    int e  = i >> 2;               // 0 .. 24575
    int rp   = e % 192;
    int g4q  = e / 192;            // q*32 + g4
    int g4   = g4q & 31;
    int q    = g4q >> 5;
    int gate = rp / 64, jj = rp & 63;
    int n = gate * 256 + q * 64 + jj;
    int k = g4 * 8 + 2 * c;
    float a = w[(size_t)n * DD + k];
    float b = w[(size_t)n * DD + k + 1];
    half2_t h = {(_Float16)a, (_Float16)b};
    wf[i] = __builtin_bit_cast(unsigned int, h);
}

// ---------- gi = seq @ w_ih^T + b_ih via f16 MFMA (unchanged, verified) ----
template <typename GiT>
__global__ __launch_bounds__(256)
void gemm_gi_mfma(const float* __restrict__ A,     // [M][256] f32
                  const float* __restrict__ W,     // [768][256] f32
                  const float* __restrict__ bias,  // [768]
                  GiT* __restrict__ C)              // [M][768]
{
    __shared__ __align__(16) _Float16 Asl[128][40];
    __shared__ __align__(16) _Float16 Bsl[128][40];

    const int tid = threadIdx.x;
    const int wv  = tid >> 6;
    const int l   = tid & 63;
    const int wm  = (wv & 1) * 64;
    const int wn  = (wv >> 1) * 64;
    const size_t bm = (size_t)blockIdx.y * 128;
    const int    bn = blockIdx.x * 128;

    const int lr = tid >> 3;
    const int lc = (tid & 7) * 4;

    f32x4 acc[4][4] = {};

    for (int kt = 0; kt < 256; kt += 32) {
#pragma unroll
        for (int rr = 0; rr < 128; rr += 32) {
            float4 av = *(const float4*)&A[(bm + lr + rr) * DD + kt + lc];
            half2_t p0 = {(_Float16)av.x, (_Float16)av.y};
            half2_t p1 = {(_Float16)av.z, (_Float16)av.w};
            uint2 pk = {__builtin_bit_cast(unsigned int, p0),
                        __builtin_bit_cast(unsigned int, p1)};
            *(uint2*)&Asl[lr + rr][lc] = pk;
        }
#pragma unroll
        for (int rr = 0; rr < 128; rr += 32) {
            float4 bv = *(const float4*)&W[(size_t)(bn + lr + rr) * DD + kt + lc];
            half2_t p0 = {(_Float16)bv.x, (_Float16)bv.y};
            half2_t p1 = {(_Float16)bv.z, (_Float16)bv.w};
            uint2 pk = {__builtin_bit_cast(unsigned int, p0),
                        __builtin_bit_cast(unsigned int, p1)};
            *(uint2*)&Bsl[lr + rr][lc] = pk;
        }
        __syncthreads();

        f16x8 af[4], bf[4];
#pragma unroll
        for (int i = 0; i < 4; ++i) {
            af[i] = *(const f16x8*)&Asl[wm + i * 16 + (l & 15)][(l >> 4) * 8];
            bf[i] = *(const f16x8*)&Bsl[wn + i * 16 + (l & 15)][(l >> 4) * 8];
        }
#pragma unroll
        for (int mi = 0; mi < 4; ++mi)
#pragma unroll
            for (int ni = 0; ni < 4; ++ni)
                acc[mi][ni] = __builtin_amdgcn_mfma_f32_16x16x32_f16(
                    af[mi], bf[ni], acc[mi][ni], 0, 0, 0);
        __syncthreads();
    }

    const int crow = (l >> 4) * 4;
    const int ccol = l & 15;
#pragma unroll
    for (int ni = 0; ni < 4; ++ni) {
        int n = bn + wn + ni * 16 + ccol;
        float bs = bias[n];
#pragma unroll
        for (int mi = 0; mi < 4; ++mi) {
#pragma unroll
            for (int q = 0; q < 4; ++q) {
                size_t m = bm + wm + mi * 16 + crow + q;
                stgi(&C[m * GG + n], acc[mi][ni][q] + bs);
            }
        }
    }
}

// ---------- 4-way split scan: 128 blocks x 256 thr, cross-CU h exchange ----
// Group = blocks {b, b+32, b+64, b+96}; quarter q owns output cols
// [64q,64q+64) of all 3 gates (192 weight rows = 96KB/step stream, 1/4 of
// the single-CU 384KB floor). h (64 f32/quarter) exchanged per step through
// agent-scope L3 with a 2-slot parity buffer + release/acquire tags.
// Lockstep chain makes slot reuse safe; tags zeroed per launch.
template <typename GiT>
__global__ void
__attribute__((amdgpu_flat_work_group_size(256, 256), amdgpu_waves_per_eu(1, 1)))
gru_scan4(const GiT* __restrict__ gi,        // [T*B][768]
          const int* __restrict__ mask,       // [T*B]
          const float* __restrict__ h0,       // [B][256]
          const uint4* __restrict__ wsplit,   // see pack_w
          const float* __restrict__ b_hh,     // [768]
          unsigned int* __restrict__ tags,    // [B][2][4]
          unsigned long long* __restrict__ exch, // [B][2][4][32] (f32 pairs)
          float* __restrict__ out,            // [T*B][256]
          float* __restrict__ hfin)           // [B][256]
{
    const int b   = blockIdx.x & 31;
    const int q   = blockIdx.x >> 5;
    const int tid = threadIdx.x;           // 0..255
    const int jj  = tid & 63;

    __shared__ __align__(16) _Float16 hhalf[HH];  // full h state, f16
    __shared__ float gh_lds[192];
    __shared__ float gi_lds[192];
    __shared__ int mlds[TT];

    for (int i = tid; i < TT; i += 256)
        mlds[i] = mask[i * BB + b];
    hhalf[tid] = (_Float16)h0[b * HH + tid];

    float h_r = 0.f;
    if (tid < 64) h_r = h0[b * HH + q * 64 + tid];

    const int  gate = tid >> 6;                       // 0..2 for tid<192
    const int  rowg = gate * 256 + q * 64 + jj;       // global gate row
    const float bhh = (tid < 192) ? b_hh[rowg] : 0.f;
    const uint4* wqb = wsplit + q * 6144 + tid;       // + g4*192

    // partner-reader mapping for tid in [64,160)
    const int rid = tid - 64;            // 0..95
    const int pi  = rid >> 5;            // 0..2
    const int qq  = pi + (pi >= q);      // the 3 partner quarters
    const int ri  = rid & 31;

    __syncthreads();

    const uint4* hu4 = (const uint4*)hhalf;  // 32 x uint4
    int a = 0;  // active-step counter (block-uniform, identical across group)

    for (int t = 0; t < TT; ++t) {
        if (mlds[t]) {
            const int par = a & 1;
            const int slot = (b * 2 + par) * 4;

            float giv = 0.f, acc0 = bhh, acc1 = 0.f, acc2 = 0.f, acc3 = 0.f;
            if (tid < 192) {
                giv = ldgi(gi + ((size_t)t * BB + b) * GG + rowg);
                // GEMV over own 192 rows: stream w (hoisted loads, 1/4 bytes)
#pragma unroll
                for (int g4 = 0; g4 < 32; ++g4) {
                    uint4 hv = hu4[g4];          // wave-uniform broadcast
                    uint4 wv = wqb[g4 * 192];
                    acc0 = fdot2(wv.x, hv.x, acc0);
                    acc1 = fdot2(wv.y, hv.y, acc1);
                    acc2 = fdot2(wv.z, hv.z, acc2);
                    acc3 = fdot2(wv.w, hv.w, acc3);
                }
                gh_lds[tid] = (acc0 + acc1) + (acc2 + acc3);
                gi_lds[tid] = giv;
            }
            __syncthreads();

            if (tid < 64) {
                // wave 0: gates + publish own h slice
                float hr = gh_lds[jj];
                float hz = gh_lds[64 + jj];
                float hn = gh_lds[128 + jj];
                float ir = gi_lds[jj];
                float iz = gi_lds[64 + jj];
                float inn = gi_lds[128 + jj];
                float r = 1.f / (1.f + __expf(-(ir + hr)));
                float z = 1.f / (1.f + __expf(-(iz + hz)));
                float e = __expf(2.f * (inn + r * hn));
                float n = 1.f - 2.f / (e + 1.f);
                float ht = (1.f - z) * n + z * h_r;
                out[((size_t)t * BB + b) * HH + q * 64 + jj] = ht;
                h_r = ht;
                hhalf[q * 64 + jj] = (_Float16)ht;
                float other = __shfl_down(ht, 1);
                if (!(jj & 1)) {
                    float2 pr = make_float2(ht, other);
                    __hip_atomic_store(&exch[(size_t)(slot + q) * 32 + (jj >> 1)],
                                       __builtin_bit_cast(unsigned long long, pr),
                                       __ATOMIC_RELAXED, __HIP_MEMORY_SCOPE_AGENT);
                }
                if (jj == 0)  // release: waits wave-0's vmcnt, then tag visible
                    __hip_atomic_store(&tags[slot + q], (unsigned int)(a + 1),
                                       __ATOMIC_RELEASE, __HIP_MEMORY_SCOPE_AGENT);
            } else if (tid < 160) {
                // waves 1-2: pull partners' h slices (overlaps wave-0 gates)
                while (__hip_atomic_load(&tags[slot + qq], __ATOMIC_ACQUIRE,
                                         __HIP_MEMORY_SCOPE_AGENT) < (unsigned int)(a + 1))
                    __builtin_amdgcn_s_sleep(1);
                unsigned long long pv =
                    __hip_atomic_load(&exch[(size_t)(slot + qq) * 32 + ri],
                                      __ATOMIC_RELAXED, __HIP_MEMORY_SCOPE_AGENT);
                float2 pr = __builtin_bit_cast(float2, pv);
                hhalf[qq * 64 + 2 * ri]     = (_Float16)pr.x;
                hhalf[qq * 64 + 2 * ri + 1] = (_Float16)pr.y;
            }
            ++a;
            __syncthreads();  // hhalf complete before next GEMV
        } else {
            // masked: own out slice is exactly zero; h unchanged; no sync
            if (tid < 64)
                out[((size_t)t * BB + b) * HH + q * 64 + jj] = 0.f;
        }
    }
    if (tid < 64) hfin[b * HH + q * 64 + tid] = h_r;
}

extern "C" void kernel_launch(void* const* d_in, const int* in_sizes, int n_in,
                              void* d_out, int out_size, void* d_ws, size_t ws_size,
                              hipStream_t stream) {
    const float* seq  = (const float*)d_in[0];
    const int*   mask = (const int*)  d_in[1];
    const float* h0   = (const float*)d_in[2];
    const float* w_ih = (const float*)d_in[3];
    const float* w_hh = (const float*)d_in[4];
    const float* b_ih = (const float*)d_in[5];
    const float* b_hh = (const float*)d_in[6];

    float* out  = (float*)d_out;
    float* hfin = out + (size_t)TT * BB * HH;

    // workspace: [tags 1KB][exch 64KB][wsplit 384KB][gi 192MB f32 (or bf16)]
    char* ws = (char*)d_ws;
    unsigned int*       tags   = (unsigned int*)ws;
    unsigned long long* exch   = (unsigned long long*)(ws + 1024);
    unsigned int*       wf     = (unsigned int*)(ws + 1024 + 65536);
    const size_t gi_off = 1024 + 65536 + (size_t)98304 * 4;  // 459776 B
    const size_t gi_elems = (size_t)TT * BB * GG;
    const size_t need_f32 = gi_off + gi_elems * 4;

    hipMemsetAsync(tags, 0, 1024, stream);
    pack_w<<<98304 / 256, 256, 0, stream>>>(w_hh, wf);

    dim3 ggrid(GG / 128, (TT * BB) / 128);  // 6 x 512
    if (ws_size >= need_f32) {
        float* gip = (float*)(ws + gi_off);
        gemm_gi_mfma<float><<<ggrid, 256, 0, stream>>>(seq, w_ih, b_ih, gip);
        gru_scan4<float><<<128, 256, 0, stream>>>(gip, mask, h0, (const uint4*)wf,
                                                  b_hh, tags, exch, out, hfin);
    } else {
        __hip_bfloat16* gip = (__hip_bfloat16*)(ws + gi_off);
        gemm_gi_mfma<__hip_bfloat16><<<ggrid, 256, 0, stream>>>(seq, w_ih, b_ih, gip);
        gru_scan4<__hip_bfloat16><<<128, 256, 0, stream>>>(gip, mask, h0,
                                                           (const uint4*)wf,
                                                           b_hh, tags, exch, out, hfin);
    }
}

// Round 12
// 2976.205 us; speedup vs baseline: 2.9101x; 2.9101x over previous
//
#include <hip/hip_runtime.h>
#include <hip/hip_bf16.h>

#define TT 2048
#define BB 32
#define DD 256
#define HH 256
#define GG 768   // 3*H

typedef _Float16 half2_t __attribute__((ext_vector_type(2)));
typedef _Float16 f16x8 __attribute__((ext_vector_type(8)));
typedef float    f32x4 __attribute__((ext_vector_type(4)));

__device__ inline float fdot2(unsigned int w, unsigned int h, float acc) {
#if __has_builtin(__builtin_amdgcn_fdot2)
    return __builtin_amdgcn_fdot2(__builtin_bit_cast(half2_t, w),
                                  __builtin_bit_cast(half2_t, h), acc, false);
#else
    half2_t a = __builtin_bit_cast(half2_t, w);
    half2_t b = __builtin_bit_cast(half2_t, h);
    return acc + (float)a.x * (float)b.x + (float)a.y * (float)b.y;
#endif
}

// ---------- helpers for fp32/bf16 workspace storage of gi ----------
__device__ inline float ldgi(const float* p) { return *p; }
__device__ inline float ldgi(const __hip_bfloat16* p) { return __bfloat162float(*p); }
__device__ inline void stgi(float* p, float v) { *p = v; }
__device__ inline void stgi(__hip_bfloat16* p, float v) { *p = __float2bfloat16(v); }

// ---------- pack w_hh [768][256] f32 into per-thread-triple layout ----------
// uint4 element e = (gate*32 + g4)*256 + t  -> w_hh row n = gate*256 + t,
// k = g4*8 + 2c for u32 component c (f16 pair {k, k+1}).
__global__ __launch_bounds__(256)
void pack_w(const float* __restrict__ w, unsigned int* __restrict__ wf) {
    int i = blockIdx.x * 256 + threadIdx.x;  // 0 .. 98303
    int c = i & 3;
    int e = i >> 2;            // (gate*32+g4)*256 + t
    int t = e & 255;
    int gg4 = e >> 8;          // gate*32 + g4
    int g4 = gg4 & 31;
    int gate = gg4 >> 5;
    int n = gate * 256 + t;
    int k = g4 * 8 + 2 * c;
    float a = w[(size_t)n * DD + k];
    float b = w[(size_t)n * DD + k + 1];
    half2_t h = {(_Float16)a, (_Float16)b};
    wf[i] = __builtin_bit_cast(unsigned int, h);
}

// ---------- gi = seq @ w_ih^T + b_ih via f16 MFMA (unchanged, verified) ----
template <typename GiT>
__global__ __launch_bounds__(256)
void gemm_gi_mfma(const float* __restrict__ A,     // [M][256] f32
                  const float* __restrict__ W,     // [768][256] f32
                  const float* __restrict__ bias,  // [768]
                  GiT* __restrict__ C)              // [M][768]
{
    __shared__ __align__(16) _Float16 Asl[128][40];
    __shared__ __align__(16) _Float16 Bsl[128][40];

    const int tid = threadIdx.x;
    const int wv  = tid >> 6;
    const int l   = tid & 63;
    const int wm  = (wv & 1) * 64;
    const int wn  = (wv >> 1) * 64;
    const size_t bm = (size_t)blockIdx.y * 128;
    const int    bn = blockIdx.x * 128;

    const int lr = tid >> 3;
    const int lc = (tid & 7) * 4;

    f32x4 acc[4][4] = {};

    for (int kt = 0; kt < 256; kt += 32) {
#pragma unroll
        for (int rr = 0; rr < 128; rr += 32) {
            float4 av = *(const float4*)&A[(bm + lr + rr) * DD + kt + lc];
            half2_t p0 = {(_Float16)av.x, (_Float16)av.y};
            half2_t p1 = {(_Float16)av.z, (_Float16)av.w};
            uint2 pk = {__builtin_bit_cast(unsigned int, p0),
                        __builtin_bit_cast(unsigned int, p1)};
            *(uint2*)&Asl[lr + rr][lc] = pk;
        }
#pragma unroll
        for (int rr = 0; rr < 128; rr += 32) {
            float4 bv = *(const float4*)&W[(size_t)(bn + lr + rr) * DD + kt + lc];
            half2_t p0 = {(_Float16)bv.x, (_Float16)bv.y};
            half2_t p1 = {(_Float16)bv.z, (_Float16)bv.w};
            uint2 pk = {__builtin_bit_cast(unsigned int, p0),
                        __builtin_bit_cast(unsigned int, p1)};
            *(uint2*)&Bsl[lr + rr][lc] = pk;
        }
        __syncthreads();

        f16x8 af[4], bf[4];
#pragma unroll
        for (int i = 0; i < 4; ++i) {
            af[i] = *(const f16x8*)&Asl[wm + i * 16 + (l & 15)][(l >> 4) * 8];
            bf[i] = *(const f16x8*)&Bsl[wn + i * 16 + (l & 15)][(l >> 4) * 8];
        }
#pragma unroll
        for (int mi = 0; mi < 4; ++mi)
#pragma unroll
            for (int ni = 0; ni < 4; ++ni)
                acc[mi][ni] = __builtin_amdgcn_mfma_f32_16x16x32_f16(
                    af[mi], bf[ni], acc[mi][ni], 0, 0, 0);
        __syncthreads();
    }

    const int crow = (l >> 4) * 4;
    const int ccol = l & 15;
#pragma unroll
    for (int ni = 0; ni < 4; ++ni) {
        int n = bn + wn + ni * 16 + ccol;
        float bs = bias[n];
#pragma unroll
        for (int mi = 0; mi < 4; ++mi) {
#pragma unroll
            for (int q = 0; q < 4; ++q) {
                size_t m = bm + wm + mi * 16 + crow + q;
                stgi(&C[m * GG + n], acc[mi][ni][q] + bs);
            }
        }
    }
}

// ---------- sequential scan: 256 thr/block, 1 wave/SIMD, resident weights --
// Thread t owns gate rows {t, 256+t, 512+t}: 384 weight u32 + ~50 working
// VGPRs, inside the 512-reg budget that waves_per_eu(1,1) grants at full
// (1-wave/SIMD) occupancy. This is the first configuration where the weight
// array FITS the hardware budget — r2-r9 asked for residency at occupancies
// where it structurally couldn't fit, so the allocator remat'd (correctly).
// Gates compute fully in-thread (no gh_lds exchange) -> LDS/step is just 32
// uniform h-broadcasts + 1 h-write.
template <typename GiT>
__global__ void
__attribute__((amdgpu_flat_work_group_size(256, 256), amdgpu_waves_per_eu(1, 1)))
gru_scan(const GiT* __restrict__ gi,        // [T*B][768]
         const int* __restrict__ mask,       // [T*B]
         const float* __restrict__ h0,       // [B][256]
         const uint4* __restrict__ wq,       // [3][32][256] uint4 (pack_w)
         const float* __restrict__ b_hh,     // [768]
         float* __restrict__ out,            // [T*B][256]
         float* __restrict__ hfin)           // [B][256]
{
    const int b = blockIdx.x;
    const int t = threadIdx.x;  // 0..255
    __shared__ __align__(16) _Float16 hhalf[HH];
    __shared__ int mlds[TT];

    // --- one-time: 384 weight u32 into VGPRs (coalesced uint4 loads) ---
    uint4 wr[32], wz[32], wn_[32];
#pragma unroll
    for (int g4 = 0; g4 < 32; ++g4) wr[g4]  = wq[(0 * 32 + g4) * 256 + t];
#pragma unroll
    for (int g4 = 0; g4 < 32; ++g4) wz[g4]  = wq[(1 * 32 + g4) * 256 + t];
#pragma unroll
    for (int g4 = 0; g4 < 32; ++g4) wn_[g4] = wq[(2 * 32 + g4) * 256 + t];

    for (int i = t; i < TT; i += 256)
        mlds[i] = mask[i * BB + b];

    float h_r = h0[b * HH + t];
    hhalf[t] = (_Float16)h_r;
    const float bhr = b_hh[t];
    const float bhz = b_hh[t + HH];
    const float bhn = b_hh[t + 2 * HH];
    __syncthreads();

    const uint4* hu4 = (const uint4*)hhalf;  // 32 x uint4

    for (int ts = 0; ts < TT; ++ts) {
        if (mlds[ts]) {
            // gi loads issued first, consumed ~800 cyc later
            const GiT* gtb = gi + ((size_t)ts * BB + b) * GG;
            float ir  = ldgi(gtb + t);
            float iz  = ldgi(gtb + t + HH);
            float inn = ldgi(gtb + t + 2 * HH);

            // three in-thread GEMV rows; h via uniform LDS broadcast
            float r0 = bhr, r1 = 0.f, r2 = 0.f, r3 = 0.f;
            float z0 = bhz, z1 = 0.f, z2 = 0.f, z3 = 0.f;
            float n0 = bhn, n1 = 0.f, n2 = 0.f, n3 = 0.f;
#pragma unroll
            for (int g4 = 0; g4 < 32; ++g4) {
                uint4 hv = hu4[g4];  // wave-uniform -> broadcast
                r0 = fdot2(wr[g4].x, hv.x, r0);
                r1 = fdot2(wr[g4].y, hv.y, r1);
                r2 = fdot2(wr[g4].z, hv.z, r2);
                r3 = fdot2(wr[g4].w, hv.w, r3);
                z0 = fdot2(wz[g4].x, hv.x, z0);
                z1 = fdot2(wz[g4].y, hv.y, z1);
                z2 = fdot2(wz[g4].z, hv.z, z2);
                z3 = fdot2(wz[g4].w, hv.w, z3);
                n0 = fdot2(wn_[g4].x, hv.x, n0);
                n1 = fdot2(wn_[g4].y, hv.y, n1);
                n2 = fdot2(wn_[g4].z, hv.z, n2);
                n3 = fdot2(wn_[g4].w, hv.w, n3);
            }
            float hr = (r0 + r1) + (r2 + r3);
            float hz = (z0 + z1) + (z2 + z3);
            float hn = (n0 + n1) + (n2 + n3);

            // gates, fully in-registers
            float r = 1.f / (1.f + __expf(-(ir + hr)));
            float z = 1.f / (1.f + __expf(-(iz + hz)));
            float e = __expf(2.f * (inn + r * hn));
            float n = 1.f - 2.f / (e + 1.f);
            float ht = (1.f - z) * n + z * h_r;

            __syncthreads();  // all hhalf reads of this step done
            out[((size_t)ts * BB + b) * HH + t] = ht;
            h_r = ht;
            hhalf[t] = (_Float16)ht;
            __syncthreads();  // h update visible before next GEMV
        } else {
            // masked: h unchanged, output row exactly zero; no barriers
            out[((size_t)ts * BB + b) * HH + t] = 0.f;
        }
    }
    hfin[b * HH + t] = h_r;
}

extern "C" void kernel_launch(void* const* d_in, const int* in_sizes, int n_in,
                              void* d_out, int out_size, void* d_ws, size_t ws_size,
                              hipStream_t stream) {
    const float* seq  = (const float*)d_in[0];
    const int*   mask = (const int*)  d_in[1];
    const float* h0   = (const float*)d_in[2];
    const float* w_ih = (const float*)d_in[3];
    const float* w_hh = (const float*)d_in[4];
    const float* b_ih = (const float*)d_in[5];
    const float* b_hh = (const float*)d_in[6];

    float* out  = (float*)d_out;
    float* hfin = out + (size_t)TT * BB * HH;

    // workspace layout: [wq: 3*32*256 uint4][gi: T*B*768 f32 (or bf16)]
    const size_t w_u32 = (size_t)128 * GG;  // 98304 u32
    unsigned int* wf = (unsigned int*)d_ws;
    const size_t gi_elems = (size_t)TT * BB * GG;
    const size_t need_f32 = w_u32 * 4 + gi_elems * 4;

    pack_w<<<(int)(w_u32 / 256), 256, 0, stream>>>(w_hh, wf);

    dim3 ggrid(GG / 128, (TT * BB) / 128);  // 6 x 512
    if (ws_size >= need_f32) {
        float* gip = (float*)d_ws + w_u32;
        gemm_gi_mfma<float><<<ggrid, 256, 0, stream>>>(seq, w_ih, b_ih, gip);
        gru_scan<float><<<BB, 256, 0, stream>>>(gip, mask, h0, (const uint4*)wf,
                                                b_hh, out, hfin);
    } else {
        __hip_bfloat16* gip = (__hip_bfloat16*)((float*)d_ws + w_u32);
        gemm_gi_mfma<__hip_bfloat16><<<ggrid, 256, 0, stream>>>(seq, w_ih, b_ih, gip);
        gru_scan<__hip_bfloat16><<<BB, 256, 0, stream>>>(gip, mask, h0,
                                                         (const uint4*)wf,
                                                         b_hh, out, hfin);
    }
}

// Round 13
// 2323.491 us; speedup vs baseline: 3.7275x; 1.2809x over previous
//
#include <hip/hip_runtime.h>
#include <hip/hip_bf16.h>

#define TT 2048
#define BB 32
#define DD 256
#define HH 256
#define GG 768   // 3*H

typedef _Float16 half2_t __attribute__((ext_vector_type(2)));
typedef _Float16 f16x8 __attribute__((ext_vector_type(8)));
typedef float    f32x4 __attribute__((ext_vector_type(4)));

__device__ inline float fdot2(unsigned int w, unsigned int h, float acc) {
#if __has_builtin(__builtin_amdgcn_fdot2)
    return __builtin_amdgcn_fdot2(__builtin_bit_cast(half2_t, w),
                                  __builtin_bit_cast(half2_t, h), acc, false);
#else
    half2_t a = __builtin_bit_cast(half2_t, w);
    half2_t b = __builtin_bit_cast(half2_t, h);
    return acc + (float)a.x * (float)b.x + (float)a.y * (float)b.y;
#endif
}

// ---------- helpers for fp32/bf16 workspace storage of gi ----------
__device__ inline float ldgi(const float* p) { return *p; }
__device__ inline float ldgi(const __hip_bfloat16* p) { return __bfloat162float(*p); }
__device__ inline void stgi(float* p, float v) { *p = v; }
__device__ inline void stgi(__hip_bfloat16* p, float v) { *p = __float2bfloat16(v); }

// ---------- pack w_hh [768][256] f32 into the 512-thread ownership layout ---
// Region A (u32 idx 0..65535):  idx=(q4*512+t)*4+i -> col=t,        k=8*q4+2i
// Region B (u32 idx 65536..):   idx2=(p4*512+t)*4+i -> col=512+(t>>1),
//                               k=(t&1)*128 + 8*p4 + 2i
__global__ __launch_bounds__(256)
void pack_w(const float* __restrict__ w, unsigned int* __restrict__ wf) {
    int i = blockIdx.x * 256 + threadIdx.x;  // 0 .. 98303
    int col, k;
    if (i < 65536) {
        int comp = i & 3, t = (i >> 2) & 511, q4 = i >> 11;
        col = t;
        k = 8 * q4 + 2 * comp;
    } else {
        int i2 = i - 65536;
        int comp = i2 & 3, t = (i2 >> 2) & 511, p4 = i2 >> 11;
        col = 512 + (t >> 1);
        k = (t & 1) * 128 + 8 * p4 + 2 * comp;
    }
    float a = w[(size_t)col * DD + k];
    float b = w[(size_t)col * DD + k + 1];
    half2_t h = {(_Float16)a, (_Float16)b};
    wf[i] = __builtin_bit_cast(unsigned int, h);
}

// ---------- gi = seq @ w_ih^T + b_ih via f16 MFMA (verified r10) ----------
template <typename GiT>
__global__ __launch_bounds__(256)
void gemm_gi_mfma(const float* __restrict__ A,     // [M][256] f32
                  const float* __restrict__ W,     // [768][256] f32
                  const float* __restrict__ bias,  // [768]
                  GiT* __restrict__ C)              // [M][768]
{
    __shared__ __align__(16) _Float16 Asl[128][40];
    __shared__ __align__(16) _Float16 Bsl[128][40];

    const int tid = threadIdx.x;
    const int wv  = tid >> 6;
    const int l   = tid & 63;
    const int wm  = (wv & 1) * 64;
    const int wn  = (wv >> 1) * 64;
    const size_t bm = (size_t)blockIdx.y * 128;
    const int    bn = blockIdx.x * 128;

    const int lr = tid >> 3;
    const int lc = (tid & 7) * 4;

    f32x4 acc[4][4] = {};

    for (int kt = 0; kt < 256; kt += 32) {
#pragma unroll
        for (int rr = 0; rr < 128; rr += 32) {
            float4 av = *(const float4*)&A[(bm + lr + rr) * DD + kt + lc];
            half2_t p0 = {(_Float16)av.x, (_Float16)av.y};
            half2_t p1 = {(_Float16)av.z, (_Float16)av.w};
            uint2 pk = {__builtin_bit_cast(unsigned int, p0),
                        __builtin_bit_cast(unsigned int, p1)};
            *(uint2*)&Asl[lr + rr][lc] = pk;
        }
#pragma unroll
        for (int rr = 0; rr < 128; rr += 32) {
            float4 bv = *(const float4*)&W[(size_t)(bn + lr + rr) * DD + kt + lc];
            half2_t p0 = {(_Float16)bv.x, (_Float16)bv.y};
            half2_t p1 = {(_Float16)bv.z, (_Float16)bv.w};
            uint2 pk = {__builtin_bit_cast(unsigned int, p0),
                        __builtin_bit_cast(unsigned int, p1)};
            *(uint2*)&Bsl[lr + rr][lc] = pk;
        }
        __syncthreads();

        f16x8 af[4], bf[4];
#pragma unroll
        for (int i = 0; i < 4; ++i) {
            af[i] = *(const f16x8*)&Asl[wm + i * 16 + (l & 15)][(l >> 4) * 8];
            bf[i] = *(const f16x8*)&Bsl[wn + i * 16 + (l & 15)][(l >> 4) * 8];
        }
#pragma unroll
        for (int mi = 0; mi < 4; ++mi)
#pragma unroll
            for (int ni = 0; ni < 4; ++ni)
                acc[mi][ni] = __builtin_amdgcn_mfma_f32_16x16x32_f16(
                    af[mi], bf[ni], acc[mi][ni], 0, 0, 0);
        __syncthreads();
    }

    const int crow = (l >> 4) * 4;
    const int ccol = l & 15;
#pragma unroll
    for (int ni = 0; ni < 4; ++ni) {
        int n = bn + wn + ni * 16 + ccol;
        float bs = bias[n];
#pragma unroll
        for (int mi = 0; mi < 4; ++mi) {
#pragma unroll
            for (int q = 0; q < 4; ++q) {
                size_t m = bm + wm + mi * 16 + crow + q;
                stgi(&C[m * GG + n], acc[mi][ni][q] + bs);
            }
        }
    }
}

// ---------- sequential scan: 512 thr, AGPR-resident weights, mask-skip -----
// The arch-VGPR file is 256/wave — 192 weight u32 can never live there with
// a working set (r2-r12 post-mortems). gfx950's unified file adds 256 AGPRs/
// wave: "+a" volatile asm pins each weight u32 into an AGPR (volatile asm
// results cannot be rematerialized; AGPR class is enforced). Cost: one
// v_accvgpr_read per use — full-rate VALU, vs ~3072cyc/step of L2 streaming.
// waves_per_eu(2,2): 2 waves/SIMD -> 512 unified regs/wave pool share;
// 192 AGPR + ~60 VGPR fits.
// Thread t: full col t (cols 0..511) + half-K of col 512+(t>>1)  [r5 layout,
// correctness-verified].
template <typename GiT>
__global__ void
__attribute__((amdgpu_flat_work_group_size(512, 512), amdgpu_waves_per_eu(2, 2)))
gru_scan(const GiT* __restrict__ gi,          // [T*B][768]
         const int* __restrict__ mask,         // [T*B]
         const float* __restrict__ h0,         // [B][256]
         const unsigned int* __restrict__ wpk, // packed, see pack_w
         const float* __restrict__ b_hh,       // [768]
         float* __restrict__ out,              // [T*B][256]
         float* __restrict__ hfin)             // [B][256]
{
    const int b = blockIdx.x;
    const int t = threadIdx.x;  // 0..511
    __shared__ __align__(16) _Float16 hhalf[HH];  // f16 state for the GEMV
    __shared__ float gh_lds[GG];
    __shared__ int mlds[TT];

    // --- one-time: 192 weight u32 into AGPRs ---
    unsigned int wA[128];
    unsigned int wB[64];
    {
        const uint4* wp = (const uint4*)wpk;
#pragma unroll
        for (int q4 = 0; q4 < 32; ++q4) {
            uint4 v = wp[q4 * 512 + t];
            wA[4 * q4 + 0] = v.x;
            wA[4 * q4 + 1] = v.y;
            wA[4 * q4 + 2] = v.z;
            wA[4 * q4 + 3] = v.w;
        }
        const uint4* wpB = wp + 32 * 512;
#pragma unroll
        for (int p4 = 0; p4 < 16; ++p4) {
            uint4 v = wpB[p4 * 512 + t];
            wB[4 * p4 + 0] = v.x;
            wB[4 * p4 + 1] = v.y;
            wB[4 * p4 + 2] = v.z;
            wB[4 * p4 + 3] = v.w;
        }
    }
#pragma unroll
    for (int q = 0; q < 128; ++q)
        asm volatile("" : "+a"(wA[q]));  // pin to AGPR, forbid remat
#pragma unroll
    for (int q = 0; q < 64; ++q)
        asm volatile("" : "+a"(wB[q]));

    for (int i = t; i < TT; i += 512)
        mlds[i] = mask[i * BB + b];

    float h_r = 0.f, bh0 = 0.f, bh1 = 0.f, bh2 = 0.f;
    if (t < HH) {
        h_r = h0[b * HH + t];
        hhalf[t] = (_Float16)h_r;
        bh0 = b_hh[t];
        bh1 = b_hh[t + HH];
        bh2 = b_hh[t + 2 * HH];
    }
    __syncthreads();

    const uint4* hu4 = (const uint4*)hhalf;                      // 32 x uint4
    const uint4* hB  = (const uint4*)(hhalf + (t & 1) * 128);    // 16 x uint4

    for (int ts = 0; ts < TT; ++ts) {
        if (mlds[ts]) {
            // gi loads issued now, consumed in the gate phase
            float ir = 0.f, iz = 0.f, inn = 0.f;
            if (t < HH) {
                const GiT* gtb = gi + ((size_t)ts * BB + b) * GG;
                ir  = ldgi(gtb + t);
                iz  = ldgi(gtb + t + HH);
                inn = ldgi(gtb + t + 2 * HH);
            }

            // --- GEMV, part A: own column t, full K (weights from AGPR) ---
            float a0 = 0.f, a1 = 0.f, a2 = 0.f, a3 = 0.f;
#pragma unroll
            for (int q4 = 0; q4 < 32; ++q4) {
                uint4 hv = hu4[q4];  // wave-uniform -> LDS broadcast
                a0 = fdot2(wA[4 * q4 + 0], hv.x, a0);
                a1 = fdot2(wA[4 * q4 + 1], hv.y, a1);
                a2 = fdot2(wA[4 * q4 + 2], hv.z, a2);
                a3 = fdot2(wA[4 * q4 + 3], hv.w, a3);
            }
            // --- GEMV, part B: half-K of column 512+(t>>1) ---
            float c0 = 0.f, c1 = 0.f, c2 = 0.f, c3 = 0.f;
#pragma unroll
            for (int p4 = 0; p4 < 16; ++p4) {
                uint4 hv = hB[p4];  // 2 addrs/wave -> 2-way, ~free (m136)
                c0 = fdot2(wB[4 * p4 + 0], hv.x, c0);
                c1 = fdot2(wB[4 * p4 + 1], hv.y, c1);
                c2 = fdot2(wB[4 * p4 + 2], hv.z, c2);
                c3 = fdot2(wB[4 * p4 + 3], hv.w, c3);
            }
            float accB = (c0 + c1) + (c2 + c3);
            float accBo = __shfl_xor(accB, 1);  // partner half-K (same wave)
            gh_lds[t] = (a0 + a1) + (a2 + a3);
            if (!(t & 1))
                gh_lds[512 + (t >> 1)] = accB + accBo;
            __syncthreads();  // gh visible; hhalf reads done

            if (t < HH) {
                float hr = gh_lds[t] + bh0;
                float hz = gh_lds[t + HH] + bh1;
                float hn = gh_lds[t + 2 * HH] + bh2;
                float r = 1.f / (1.f + __expf(-(ir + hr)));
                float z = 1.f / (1.f + __expf(-(iz + hz)));
                float e = __expf(2.f * (inn + r * hn));
                float n = 1.f - 2.f / (e + 1.f);
                float ht = (1.f - z) * n + z * h_r;
                out[((size_t)ts * BB + b) * HH + t] = ht;
                h_r = ht;
                hhalf[t] = (_Float16)ht;
            }
            __syncthreads();  // h update visible before next GEMV
        } else {
            // masked: h unchanged, output row exactly zero; no barriers
            if (t < HH)
                out[((size_t)ts * BB + b) * HH + t] = 0.f;
        }
    }
    if (t < HH) hfin[b * HH + t] = h_r;
}

extern "C" void kernel_launch(void* const* d_in, const int* in_sizes, int n_in,
                              void* d_out, int out_size, void* d_ws, size_t ws_size,
                              hipStream_t stream) {
    const float* seq  = (const float*)d_in[0];
    const int*   mask = (const int*)  d_in[1];
    const float* h0   = (const float*)d_in[2];
    const float* w_ih = (const float*)d_in[3];
    const float* w_hh = (const float*)d_in[4];
    const float* b_ih = (const float*)d_in[5];
    const float* b_hh = (const float*)d_in[6];

    float* out  = (float*)d_out;
    float* hfin = out + (size_t)TT * BB * HH;

    // workspace layout: [wpk: 128*768 u32][gi: T*B*768 f32 (or bf16 fallback)]
    const size_t wpk_elems = (size_t)128 * GG;
    unsigned int* wpk = (unsigned int*)d_ws;
    const size_t gi_elems = (size_t)TT * BB * GG;
    const size_t need_f32 = wpk_elems * 4 + gi_elems * 4;

    pack_w<<<(int)(wpk_elems / 256), 256, 0, stream>>>(w_hh, wpk);

    dim3 ggrid(GG / 128, (TT * BB) / 128);  // 6 x 512
    if (ws_size >= need_f32) {
        float* gip = (float*)d_ws + wpk_elems;
        gemm_gi_mfma<float><<<ggrid, 256, 0, stream>>>(seq, w_ih, b_ih, gip);
        gru_scan<float><<<BB, 512, 0, stream>>>(gip, mask, h0, wpk, b_hh, out, hfin);
    } else {
        __hip_bfloat16* gip = (__hip_bfloat16*)((float*)d_ws + wpk_elems);
        gemm_gi_mfma<__hip_bfloat16><<<ggrid, 256, 0, stream>>>(seq, w_ih, b_ih, gip);
        gru_scan<__hip_bfloat16><<<BB, 512, 0, stream>>>(gip, mask, h0, wpk, b_hh, out, hfin);
    }
}

// Round 14
// 1498.625 us; speedup vs baseline: 5.7792x; 1.5504x over previous
//
#include <hip/hip_runtime.h>
#include <hip/hip_bf16.h>

#define TT 2048
#define BB 32
#define DD 256
#define HH 256
#define GG 768   // 3*H

typedef _Float16 half2_t __attribute__((ext_vector_type(2)));
typedef _Float16 f16x8 __attribute__((ext_vector_type(8)));
typedef float    f32x4 __attribute__((ext_vector_type(4)));
typedef unsigned int u32x4 __attribute__((ext_vector_type(4)));

// ---------- helpers for fp32/bf16 workspace storage of gi ----------
__device__ inline float ldgi(const float* p) { return *p; }
__device__ inline float ldgi(const __hip_bfloat16* p) { return __bfloat162float(*p); }
__device__ inline void stgi(float* p, float v) { *p = v; }
__device__ inline void stgi(__hip_bfloat16* p, float v) { *p = __float2bfloat16(v); }

// ---------- pack w_hh [768][256] f32 into per-wave MFMA B-fragments ----------
// (verbatim from round 3 — refcheck-verified layout)
// flat u32 index: (((wv*6+nt)*8+kt)*64+l)*4+r
//   n = wv*96 + nt*16 + (l&15)
//   k = kt*32 + (l>>4)*8 + 2r   (u32 = f16 pair {k, k+1}, low half first)
__global__ __launch_bounds__(256)
void pack_w(const float* __restrict__ w, unsigned int* __restrict__ wf) {
    int idx = blockIdx.x * 256 + threadIdx.x;  // 0 .. 98303
    int r    = idx & 3;
    int l    = (idx >> 2) & 63;
    int kt   = (idx >> 8) & 7;
    int rest = idx >> 11;            // wv*6 + nt, 0..47
    int nt = rest % 6, wv = rest / 6;
    int n = wv * 96 + nt * 16 + (l & 15);
    int k = kt * 32 + (l >> 4) * 8 + 2 * r;
    float a = w[(size_t)n * DD + k];
    float b = w[(size_t)n * DD + k + 1];
    half2_t h = {(_Float16)a, (_Float16)b};
    wf[idx] = __builtin_bit_cast(unsigned int, h);
}

// ---------- gi = seq @ w_ih^T + b_ih via f16 MFMA (verified r10) ----------
template <typename GiT>
__global__ __launch_bounds__(256)
void gemm_gi_mfma(const float* __restrict__ A,     // [M][256] f32
                  const float* __restrict__ W,     // [768][256] f32
                  const float* __restrict__ bias,  // [768]
                  GiT* __restrict__ C)              // [M][768]
{
    __shared__ __align__(16) _Float16 Asl[128][40];
    __shared__ __align__(16) _Float16 Bsl[128][40];

    const int tid = threadIdx.x;
    const int wv  = tid >> 6;
    const int l   = tid & 63;
    const int wm  = (wv & 1) * 64;
    const int wn  = (wv >> 1) * 64;
    const size_t bm = (size_t)blockIdx.y * 128;
    const int    bn = blockIdx.x * 128;

    const int lr = tid >> 3;
    const int lc = (tid & 7) * 4;

    f32x4 acc[4][4] = {};

    for (int kt = 0; kt < 256; kt += 32) {
#pragma unroll
        for (int rr = 0; rr < 128; rr += 32) {
            float4 av = *(const float4*)&A[(bm + lr + rr) * DD + kt + lc];
            half2_t p0 = {(_Float16)av.x, (_Float16)av.y};
            half2_t p1 = {(_Float16)av.z, (_Float16)av.w};
            uint2 pk = {__builtin_bit_cast(unsigned int, p0),
                        __builtin_bit_cast(unsigned int, p1)};
            *(uint2*)&Asl[lr + rr][lc] = pk;
        }
#pragma unroll
        for (int rr = 0; rr < 128; rr += 32) {
            float4 bv = *(const float4*)&W[(size_t)(bn + lr + rr) * DD + kt + lc];
            half2_t p0 = {(_Float16)bv.x, (_Float16)bv.y};
            half2_t p1 = {(_Float16)bv.z, (_Float16)bv.w};
            uint2 pk = {__builtin_bit_cast(unsigned int, p0),
                        __builtin_bit_cast(unsigned int, p1)};
            *(uint2*)&Bsl[lr + rr][lc] = pk;
        }
        __syncthreads();

        f16x8 af[4], bf[4];
#pragma unroll
        for (int i = 0; i < 4; ++i) {
            af[i] = *(const f16x8*)&Asl[wm + i * 16 + (l & 15)][(l >> 4) * 8];
            bf[i] = *(const f16x8*)&Bsl[wn + i * 16 + (l & 15)][(l >> 4) * 8];
        }
#pragma unroll
        for (int mi = 0; mi < 4; ++mi)
#pragma unroll
            for (int ni = 0; ni < 4; ++ni)
                acc[mi][ni] = __builtin_amdgcn_mfma_f32_16x16x32_f16(
                    af[mi], bf[ni], acc[mi][ni], 0, 0, 0);
        __syncthreads();
    }

    const int crow = (l >> 4) * 4;
    const int ccol = l & 15;
#pragma unroll
    for (int ni = 0; ni < 4; ++ni) {
        int n = bn + wn + ni * 16 + ccol;
        float bs = bias[n];
#pragma unroll
        for (int mi = 0; mi < 4; ++mi) {
#pragma unroll
            for (int q = 0; q < 4; ++q) {
                size_t m = bm + wm + mi * 16 + crow + q;
                stgi(&C[m * GG + n], acc[mi][ni][q] + bs);
            }
        }
    }
}

// ---------- MFMA scan: 1 batch/block, weights pinned in AGPRs ----------
// Wave wv owns output cols [wv*96, wv*96+96) as 6 N-tiles; B-fragments live
// in 192 AGPRs via volatile "+a" pins. MFMA reads AGPRs natively (ISA §10),
// so — unlike r13's fdot2 path — keeping them resident costs the allocator
// NOTHING (no accvgpr_read per use), and re-executing a volatile asm is
// illegal, so the loads cannot be remat'd into the loop. A-operand: all 16
// lanes of a group read the SAME 16B of h from LDS (row 0 replicated across
// the M dim by construction) -> conflict-free broadcast; C rows all equal,
// row 0 read at lanes<16, reg 0. Mask-skip restored (1 batch/block).
// Budget: 192 AGPR + ~50 VGPR < 256/wave at 2 waves/SIMD.
template <typename GiT>
__global__ void
__attribute__((amdgpu_flat_work_group_size(512, 512), amdgpu_waves_per_eu(2, 2)))
gru_scan_mfma(const GiT* __restrict__ gi,          // [T*B][768]
              const int* __restrict__ mask,         // [T*B]
              const float* __restrict__ h0,         // [B][256]
              const unsigned int* __restrict__ wf,  // packed B-fragments
              const float* __restrict__ b_hh,       // [768]
              float* __restrict__ out,              // [T*B][256]
              float* __restrict__ hfin)             // [B][256]
{
    const int b   = blockIdx.x;
    const int tid = threadIdx.x;   // 0..511
    const int wv  = tid >> 6;      // 0..7
    const int l   = tid & 63;

    __shared__ __align__(16) _Float16 hhalf[HH];  // h state, f16
    __shared__ float gh_lds[GG];
    __shared__ int mlds[TT];

    // --- one-time: weights into AGPRs (volatile pin forbids remat) ---
    u32x4 w[6][8];
    {
        const u32x4* wp = (const u32x4*)wf;
#pragma unroll
        for (int nt = 0; nt < 6; ++nt)
#pragma unroll
            for (int kt = 0; kt < 8; ++kt)
                w[nt][kt] = wp[(size_t)((wv * 6 + nt) * 8 + kt) * 64 + l];
    }
#pragma unroll
    for (int nt = 0; nt < 6; ++nt)
#pragma unroll
        for (int kt = 0; kt < 8; ++kt)
            asm volatile("" : "+a"(w[nt][kt]));  // pin to AGPR tuple

    for (int i = tid; i < TT; i += 512)
        mlds[i] = mask[i * BB + b];

    float h_r = 0.f, bh0 = 0.f, bh1 = 0.f, bh2 = 0.f;
    if (tid < HH) {
        h_r = h0[b * HH + tid];
        hhalf[tid] = (_Float16)h_r;
        bh0 = b_hh[tid];
        bh1 = b_hh[tid + HH];
        bh2 = b_hh[tid + 2 * HH];
    }
    __syncthreads();

    // A-operand broadcast source: 16-lane group g=(l>>4) reads h[kt*32+g*8 ..]
    const _Float16* abase = hhalf + (l >> 4) * 8;

    for (int ts = 0; ts < TT; ++ts) {
        if (mlds[ts]) {
            // gi loads first (consumed in the gate phase, ~700 cyc later)
            float ir = 0.f, iz = 0.f, inn = 0.f;
            if (tid < HH) {
                const GiT* gtb = gi + ((size_t)ts * BB + b) * GG;
                ir  = ldgi(gtb + tid);
                iz  = ldgi(gtb + tid + HH);
                inn = ldgi(gtb + tid + 2 * HH);
            }

            // --- GEMV on the matrix pipe: gh[768] = h @ w_hh^T ---
            f32x4 acc[6] = {};
#pragma unroll
            for (int kt = 0; kt < 8; ++kt) {
                f16x8 a = *(const f16x8*)(abase + kt * 32);  // LDS broadcast
#pragma unroll
                for (int nt = 0; nt < 6; ++nt)
                    acc[nt] = __builtin_amdgcn_mfma_f32_16x16x32_f16(
                        a, __builtin_bit_cast(f16x8, w[nt][kt]), acc[nt],
                        0, 0, 0);
            }
            // C row 0 (all rows equal): lanes 0-15, reg 0
            if (l < 16) {
#pragma unroll
                for (int nt = 0; nt < 6; ++nt)
                    gh_lds[wv * 96 + nt * 16 + l] = acc[nt][0];
            }
            __syncthreads();  // gh visible; hhalf reads done

            if (tid < HH) {
                float hr = gh_lds[tid] + bh0;
                float hz = gh_lds[tid + HH] + bh1;
                float hn = gh_lds[tid + 2 * HH] + bh2;
                float r = 1.f / (1.f + __expf(-(ir + hr)));
                float z = 1.f / (1.f + __expf(-(iz + hz)));
                float e = __expf(2.f * (inn + r * hn));
                float n = 1.f - 2.f / (e + 1.f);
                float ht = (1.f - z) * n + z * h_r;
                out[((size_t)ts * BB + b) * HH + tid] = ht;
                h_r = ht;
                hhalf[tid] = (_Float16)ht;
            }
            __syncthreads();  // h update visible before next GEMV
        } else {
            // masked: h unchanged, output row exactly zero; no barriers
            if (tid < HH)
                out[((size_t)ts * BB + b) * HH + tid] = 0.f;
        }
    }
    if (tid < HH) hfin[b * HH + tid] = h_r;
}

extern "C" void kernel_launch(void* const* d_in, const int* in_sizes, int n_in,
                              void* d_out, int out_size, void* d_ws, size_t ws_size,
                              hipStream_t stream) {
    const float* seq  = (const float*)d_in[0];
    const int*   mask = (const int*)  d_in[1];
    const float* h0   = (const float*)d_in[2];
    const float* w_ih = (const float*)d_in[3];
    const float* w_hh = (const float*)d_in[4];
    const float* b_ih = (const float*)d_in[5];
    const float* b_hh = (const float*)d_in[6];

    float* out  = (float*)d_out;
    float* hfin = out + (size_t)TT * BB * HH;

    // workspace layout: [wf: 98304 u32][gi: T*B*768 f32 (or bf16 fallback)]
    const size_t wf_elems = (size_t)128 * GG;  // 98304
    unsigned int* wf = (unsigned int*)d_ws;
    const size_t gi_elems = (size_t)TT * BB * GG;
    const size_t need_f32 = wf_elems * 4 + gi_elems * 4;

    pack_w<<<(int)(wf_elems / 256), 256, 0, stream>>>(w_hh, wf);

    dim3 ggrid(GG / 128, (TT * BB) / 128);  // 6 x 512
    if (ws_size >= need_f32) {
        float* gip = (float*)d_ws + wf_elems;
        gemm_gi_mfma<float><<<ggrid, 256, 0, stream>>>(seq, w_ih, b_ih, gip);
        gru_scan_mfma<float><<<BB, 512, 0, stream>>>(gip, mask, h0, wf, b_hh,
                                                     out, hfin);
    } else {
        __hip_bfloat16* gip = (__hip_bfloat16*)((float*)d_ws + wf_elems);
        gemm_gi_mfma<__hip_bfloat16><<<ggrid, 256, 0, stream>>>(seq, w_ih, b_ih, gip);
        gru_scan_mfma<__hip_bfloat16><<<BB, 512, 0, stream>>>(gip, mask, h0, wf,
                                                              b_hh, out, hfin);
    }
}